// Round 2
// baseline (1804.486 us; speedup 1.0000x reference)
//
#include <hip/hip_runtime.h>

// LiquidNN LTC: B=512, S=512, D=H=128, O=1, UNFOLDS=6, dt=0.1, tau=1.
// R1 -> R2 change: output coarsening R=2. Block=128 threads (2 waves), 1 row/block.
// Thread t: og = t>>1, kh = t&1 (K-half). Computes partials for TWO outputs
// o0=og and o1=og+64 from ONE 64-element h slice (8 ds_read_b128 -> 64 dot2),
// halving LDS-pipe traffic per CU (the R1 bottleneck: 5376 cyc/step/CU LDS vs
// 7030 total). Lane-designated output od = kh? og+64 : og owns h/tanh/bias.

typedef _Float16 v2h __attribute__((ext_vector_type(2)));

#define S_LEN 512
#define HDIM 128
#define NUNF 6
#define DTC 0.1f

__device__ __forceinline__ float fast_tanh(float y) {
    // tanh(y) = 1 - 2/(e^{2y}+1); exp+rcp based, NaN-free at +-inf
    float u = __expf(2.0f * y);
    return 1.0f - __fdividef(2.0f, u + 1.0f);
}

__global__ __launch_bounds__(128, 2)
void ltc_kernel(const float* __restrict__ x,
                const float* __restrict__ W_in,
                const float* __restrict__ b_in,
                const float* __restrict__ W_r,
                const float* __restrict__ b_r,
                const float* __restrict__ W_fc,
                const float* __restrict__ b_fc,
                float* __restrict__ out)
{
    const int b     = blockIdx.x;
    const int tid   = threadIdx.x;   // 0..127
    const int og    = tid >> 1;      // 0..63
    const int kh    = tid & 1;       // K-half
    const int kbase = kh * 64;       // element offset into K
    const int o0    = og;            // first owned output (partials on both lanes)
    const int o1    = og + 64;       // second owned output
    const int od    = kh ? o1 : o0;  // designated output for THIS lane

    __shared__ __align__(16) _Float16 hbuf[2][HDIM];
    __shared__ __align__(16) _Float16 xbuf[2][HDIM];
    __shared__ float red[2];

    // ---- one-time: weight rows (2 outputs x K-half) into registers as f16 pairs ----
    v2h wr0[32], wr1[32], wi0[32], wi1[32];   // 128 VGPRs total
    {
        const float4* wr0p = reinterpret_cast<const float4*>(W_r  + o0 * HDIM + kbase);
        const float4* wr1p = reinterpret_cast<const float4*>(W_r  + o1 * HDIM + kbase);
        const float4* wi0p = reinterpret_cast<const float4*>(W_in + o0 * HDIM + kbase);
        const float4* wi1p = reinterpret_cast<const float4*>(W_in + o1 * HDIM + kbase);
#pragma unroll
        for (int j = 0; j < 16; ++j) {
            float4 f;
            f = wr0p[j]; wr0[2*j] = v2h{(_Float16)f.x,(_Float16)f.y}; wr0[2*j+1] = v2h{(_Float16)f.z,(_Float16)f.w};
            f = wr1p[j]; wr1[2*j] = v2h{(_Float16)f.x,(_Float16)f.y}; wr1[2*j+1] = v2h{(_Float16)f.z,(_Float16)f.w};
            f = wi0p[j]; wi0[2*j] = v2h{(_Float16)f.x,(_Float16)f.y}; wi0[2*j+1] = v2h{(_Float16)f.z,(_Float16)f.w};
            f = wi1p[j]; wi1[2*j] = v2h{(_Float16)f.x,(_Float16)f.y}; wi1[2*j+1] = v2h{(_Float16)f.z,(_Float16)f.w};
        }
    }
    const float binv = b_in[od];
    const float brv  = b_r[od];

    const float* x_row = x + (size_t)b * S_LEN * HDIM;

    float h_d = 0.0f;   // fp32 authoritative h for designated output od

    // prologue: stage x[b,0,:], zero h LDS copy
    xbuf[0][tid] = (_Float16)x_row[tid];
    hbuf[0][tid] = (_Float16)0.0f;
    __syncthreads();

    for (int s = 0; s < S_LEN; ++s) {
        // prefetch next step's x (HBM latency hidden under this step's compute)
        float xnext = 0.0f;
        if (s + 1 < S_LEN)
            xnext = x_row[(size_t)(s + 1) * HDIM + tid];

        // ---- input map: xin_od = x[b,s,:].W_in[od,:] + b_in[od] ----
        float xin_d;
        {
            const float4* hp = reinterpret_cast<const float4*>(&xbuf[s & 1][kbase]);
            float4 hv[8];
#pragma unroll
            for (int j = 0; j < 8; ++j) hv[j] = hp[j];
            const v2h* hh = reinterpret_cast<const v2h*>(hv);
            float a0 = 0.f, a1 = 0.f, b0 = 0.f, b1 = 0.f;
#pragma unroll
            for (int j = 0; j < 32; j += 2) {
                a0 = __builtin_amdgcn_fdot2(wi0[j],   hh[j],   a0, false);
                a1 = __builtin_amdgcn_fdot2(wi0[j+1], hh[j+1], a1, false);
                b0 = __builtin_amdgcn_fdot2(wi1[j],   hh[j],   b0, false);
                b1 = __builtin_amdgcn_fdot2(wi1[j+1], hh[j+1], b1, false);
            }
            float p0 = a0 + a1;            // partial for o0 (this K-half)
            float p1 = b0 + b1;            // partial for o1
            float f0 = p0 + __shfl_xor(p0, 1);
            float f1 = p1 + __shfl_xor(p1, 1);
            xin_d = (kh ? f1 : f0) + binv;
        }

        // ---- 6 ODE unfolds ----
#pragma unroll
        for (int u = 0; u < NUNF; ++u) {
            const float4* hp = reinterpret_cast<const float4*>(&hbuf[u & 1][kbase]);
            float4 hv[8];
#pragma unroll
            for (int j = 0; j < 8; ++j) hv[j] = hp[j];
            const v2h* hh = reinterpret_cast<const v2h*>(hv);
            float a0 = 0.f, a1 = 0.f, b0 = 0.f, b1 = 0.f;
#pragma unroll
            for (int j = 0; j < 32; j += 2) {
                a0 = __builtin_amdgcn_fdot2(wr0[j],   hh[j],   a0, false);
                a1 = __builtin_amdgcn_fdot2(wr0[j+1], hh[j+1], a1, false);
                b0 = __builtin_amdgcn_fdot2(wr1[j],   hh[j],   b0, false);
                b1 = __builtin_amdgcn_fdot2(wr1[j+1], hh[j+1], b1, false);
            }
            float p0 = a0 + a1;
            float p1 = b0 + b1;
            float f0 = p0 + __shfl_xor(p0, 1);
            float f1 = p1 + __shfl_xor(p1, 1);
            float yv = xin_d + brv + (kh ? f1 : f0);
            float v  = fast_tanh(yv);
            h_d = h_d + DTC * (v - h_d);        // tau=1: h += dt*(-h+v)
            hbuf[(u + 1) & 1][od] = (_Float16)h_d;   // all 128 lanes write distinct slots
            if (u == NUNF - 1 && s + 1 < S_LEN)
                xbuf[(s + 1) & 1][tid] = (_Float16)xnext;
            __syncthreads();
        }
    }

    // ---- epilogue: out[b] = h . W_fc[0,:] + b_fc ----
    float partial = h_d * W_fc[od];
#pragma unroll
    for (int d = 1; d < 64; d <<= 1) partial += __shfl_xor(partial, d);
    if ((tid & 63) == 0) red[tid >> 6] = partial;
    __syncthreads();
    if (tid == 0) out[b] = red[0] + red[1] + b_fc[0];
}

extern "C" void kernel_launch(void* const* d_in, const int* in_sizes, int n_in,
                              void* d_out, int out_size, void* d_ws, size_t ws_size,
                              hipStream_t stream) {
    const float* x    = (const float*)d_in[0];
    const float* W_in = (const float*)d_in[1];
    const float* b_in = (const float*)d_in[2];
    const float* W_r  = (const float*)d_in[3];
    const float* b_r  = (const float*)d_in[4];
    const float* W_fc = (const float*)d_in[5];
    const float* b_fc = (const float*)d_in[6];
    float* outp = (float*)d_out;
    (void)in_sizes; (void)n_in; (void)out_size; (void)d_ws; (void)ws_size;
    ltc_kernel<<<dim3(512), dim3(128), 0, stream>>>(x, W_in, b_in, W_r, b_r, W_fc, b_fc, outp);
}